// Round 2
// baseline (1109.626 us; speedup 1.0000x reference)
//
#include <hip/hip_runtime.h>
#include <cstdint>

typedef __bf16 bf16;
typedef __bf16 bf16x8 __attribute__((ext_vector_type(8)));
typedef float  f32x4  __attribute__((ext_vector_type(4)));

__device__ __forceinline__ void g2l16(const bf16* g, bf16* l) {
  __builtin_amdgcn_global_load_lds(
      (const __attribute__((address_space(1))) unsigned int*)g,
      (__attribute__((address_space(3))) unsigned int*)l, 16, 0, 0);
}

// ---------- cast fp32 weights -> bf16, with zero padding ----------
__global__ __launch_bounds__(256) void cast_pad(const float* __restrict__ src, bf16* __restrict__ dst,
                                                int cd, int rs, int cs) {
  int c = blockIdx.x * 256 + threadIdx.x;
  int r = blockIdx.y;
  if (c >= cd) return;
  float v = (r < rs && c < cs) ? src[(size_t)r * cs + c] : 0.f;
  dst[(size_t)r * cd + c] = (bf16)v;
}

// ---------- layernorm (D=768) + cast to bf16 ----------
__global__ __launch_bounds__(256) void ln_cast(const float* __restrict__ x, const float* __restrict__ w,
                                               const float* __restrict__ b, bf16* __restrict__ out) {
  const int row = blockIdx.x;
  const int tid = threadIdx.x;
  const float* xr = x + (size_t)row * 768;
  float v0 = xr[tid], v1 = xr[tid + 256], v2 = xr[tid + 512];
  float s = v0 + v1 + v2;
  __shared__ float red[8];
  #pragma unroll
  for (int o = 32; o; o >>= 1) s += __shfl_down(s, o);
  if ((tid & 63) == 0) red[tid >> 6] = s;
  __syncthreads();
  float mean = (red[0] + red[1] + red[2] + red[3]) * (1.f / 768.f);
  float d0 = v0 - mean, d1 = v1 - mean, d2 = v2 - mean;
  float q = d0 * d0 + d1 * d1 + d2 * d2;
  #pragma unroll
  for (int o = 32; o; o >>= 1) q += __shfl_down(q, o);
  if ((tid & 63) == 0) red[4 + (tid >> 6)] = q;
  __syncthreads();
  float var = (red[4] + red[5] + red[6] + red[7]) * (1.f / 768.f);
  float inv = rsqrtf(var + 1e-5f);
  bf16* orow = out + (size_t)row * 768;
  orow[tid]       = (bf16)(d0 * inv * w[tid]       + b[tid]);
  orow[tid + 256] = (bf16)(d1 * inv * w[tid + 256] + b[tid + 256]);
  orow[tid + 512] = (bf16)(d2 * inv * w[tid + 512] + b[tid + 512]);
}

// ---------- causal depthwise conv (width 4) + SiLU ----------
__global__ __launch_bounds__(256) void conv_silu(const bf16* __restrict__ xz, const float* __restrict__ cw,
                                                 const float* __restrict__ cb, bf16* __restrict__ u) {
  int c = blockIdx.x * 256 + threadIdx.x;   // 0..1535
  int r = blockIdx.y;                        // 0..8191 (b*2048+t)
  int t = r & 2047;
  const float4 wv = ((const float4*)cw)[c];
  float acc = cb[c];
  const bf16* col = xz + c;
  if (t >= 3) {
    acc += (float)col[(size_t)(r - 3) * 3072] * wv.x;
    acc += (float)col[(size_t)(r - 2) * 3072] * wv.y;
    acc += (float)col[(size_t)(r - 1) * 3072] * wv.z;
  } else {
    if (t >= 2) acc += (float)col[(size_t)(r - 2) * 3072] * wv.y;
    if (t >= 1) acc += (float)col[(size_t)(r - 1) * 3072] * wv.z;
  }
  acc += (float)col[(size_t)r * 3072] * wv.w;
  float sg = 1.f / (1.f + __expf(-acc));
  u[(size_t)r * 1536 + c] = (bf16)(acc * sg);
}

// ---------- MFMA GEMM: C(M,N) = A(M,K) @ B(N,K)^T, 128x128 tile, BK=32 ----------
// EPI: 0 = bf16 store; 1 = f32 + bf16 dual store; 2 = softplus(v+aux[col]) bf16;
//      3 = v + aux2[idx] f32; 4 = relu(v+aux[col]) bf16; 5 = v + aux[col] + aux2[idx] f32
template<int EPI>
__global__ __launch_bounds__(256) void gemm_bt(
    const bf16* __restrict__ A, const bf16* __restrict__ B,
    int N, int K, int lda, int ldb,
    void* __restrict__ C0, void* __restrict__ C1,
    const float* __restrict__ aux, const float* __restrict__ aux2)
{
  __shared__ alignas(16) bf16 As[4096];
  __shared__ alignas(16) bf16 Bs[4096];
  const int tid = threadIdx.x;
  const int w = tid >> 6, l = tid & 63;
  const int m0 = blockIdx.y * 128, n0 = blockIdx.x * 128;
  const int wr = (w >> 1) * 64, wc = (w & 1) * 64;

  const int srow = tid >> 2;
  const int scol = (tid & 3) * 8;
  const bf16* ag  = A + (size_t)(m0 + srow) * lda + scol;
  const bf16* ag2 = A + (size_t)(m0 + 64 + srow) * lda + scol;
  const bf16* bg  = B + (size_t)(n0 + srow) * ldb + scol;
  const bf16* bg2 = B + (size_t)(n0 + 64 + srow) * ldb + scol;
  bf16* lA  = &As[w * 512];
  bf16* lA2 = &As[2048 + w * 512];
  bf16* lB  = &Bs[w * 512];
  bf16* lB2 = &Bs[2048 + w * 512];

  f32x4 acc[4][4] = {};
  const int fr = l & 15, kb = (l >> 4) * 8;

  for (int k0 = 0; k0 < K; k0 += 32) {
    g2l16(ag  + k0, lA);
    g2l16(ag2 + k0, lA2);
    g2l16(bg  + k0, lB);
    g2l16(bg2 + k0, lB2);
    __syncthreads();
    bf16x8 af[4], bfr[4];
    #pragma unroll
    for (int i = 0; i < 4; ++i) {
      af[i]  = *(const bf16x8*)&As[(wr + i * 16 + fr) * 32 + kb];
      bfr[i] = *(const bf16x8*)&Bs[(wc + i * 16 + fr) * 32 + kb];
    }
    #pragma unroll
    for (int i = 0; i < 4; ++i)
      #pragma unroll
      for (int j = 0; j < 4; ++j)
        acc[i][j] = __builtin_amdgcn_mfma_f32_16x16x32_bf16(af[i], bfr[j], acc[i][j], 0, 0, 0);
    __syncthreads();
  }

  const int fq = (l >> 4) * 4;
  #pragma unroll
  for (int i = 0; i < 4; ++i) {
    #pragma unroll
    for (int j = 0; j < 4; ++j) {
      int row = m0 + wr + i * 16 + fq;
      int col = n0 + wc + j * 16 + fr;
      f32x4 v = acc[i][j];
      #pragma unroll
      for (int jj = 0; jj < 4; ++jj) {
        size_t idx = (size_t)(row + jj) * N + col;
        float val = v[jj];
        if constexpr (EPI == 0) {
          ((bf16*)C0)[idx] = (bf16)val;
        } else if constexpr (EPI == 1) {
          ((float*)C0)[idx] = val;
          ((bf16*)C1)[idx] = (bf16)val;
        } else if constexpr (EPI == 2) {
          float xv = val + aux[col];
          float sp = (xv > 20.f) ? xv : log1pf(__expf(xv));
          ((bf16*)C0)[idx] = (bf16)sp;
        } else if constexpr (EPI == 3) {
          ((float*)C0)[idx] = val + aux2[idx];
        } else if constexpr (EPI == 4) {
          float xv = val + aux[col];
          ((bf16*)C0)[idx] = (bf16)(xv > 0.f ? xv : 0.f);
        } else if constexpr (EPI == 5) {
          ((float*)C0)[idx] = val + aux[col] + aux2[idx];
        }
      }
    }
  }
}

// ---------- selective scan, fused gating: one thread per (b, channel, state) ----------
#define ST 128
__global__ __launch_bounds__(256) void scan_fuse(
    const bf16* __restrict__ dtb, const bf16* __restrict__ ub, const bf16* __restrict__ xzb,
    const float* __restrict__ xdbl, const float* __restrict__ A_log, const float* __restrict__ Dskip,
    bf16* __restrict__ yg)
{
  __shared__ float bc_s[ST * 32];   // [t][0..15]=B, [t][16..31]=C
  __shared__ float dt_s[ST * 16];
  __shared__ float du_s[ST * 16];   // u
  __shared__ float g_s[ST * 16];    // silu(z)
  __shared__ bf16  ys[ST * 16];

  const int tid = threadIdx.x;
  const int cg = blockIdx.x % 96;
  const int b  = blockIdx.x / 96;
  const int c0 = cg * 16;
  const int n = tid & 15, cl = tid >> 4;
  const int c = c0 + cl;
  const size_t rowbase = (size_t)b * 2048;

  const float alog2e = -__expf(A_log[c * 16 + n]) * 1.44269504f;
  const float dsk = Dskip[c];
  float h = 0.f;

  for (int chunk = 0; chunk < 2048 / ST; ++chunk) {
    const int tb = chunk * ST;
    if (chunk) {
      for (int i = tid; i < ST * 16; i += 256) {
        int tr = i >> 4, ccl = i & 15;
        yg[(rowbase + tb - ST + tr) * 1536 + c0 + ccl] = ys[i];
      }
    }
    for (int i = tid; i < ST * 32; i += 256) {
      int tr = i >> 5, q = i & 31;
      bc_s[i] = xdbl[(rowbase + tb + tr) * 128 + 48 + q];
    }
    for (int i = tid; i < ST * 16; i += 256) {
      int tr = i >> 4, ccl = i & 15;
      size_t gr = rowbase + tb + tr;
      dt_s[i] = (float)dtb[gr * 1536 + c0 + ccl];
      du_s[i] = (float)ub[gr * 1536 + c0 + ccl];
      float zv = (float)xzb[gr * 3072 + 1536 + c0 + ccl];
      g_s[i] = zv / (1.f + __expf(-zv));
    }
    __syncthreads();
    for (int tr = 0; tr < ST; ++tr) {
      float dtv = dt_s[tr * 16 + cl];
      float uv  = du_s[tr * 16 + cl];
      float e = exp2f(dtv * alog2e);
      float bn = bc_s[tr * 32 + n];
      float cn = bc_s[tr * 32 + 16 + n];
      h = h * e + dtv * uv * bn;
      float p = h * cn;
      p += __shfl_xor(p, 1);
      p += __shfl_xor(p, 2);
      p += __shfl_xor(p, 4);
      p += __shfl_xor(p, 8);
      if (n == 0) ys[tr * 16 + cl] = (bf16)((p + uv * dsk) * g_s[tr * 16 + cl]);
    }
    __syncthreads();
  }
  for (int i = tid; i < ST * 16; i += 256) {
    int tr = i >> 4, ccl = i & 15;
    yg[(rowbase + 2048 - ST + tr) * 1536 + c0 + ccl] = ys[i];
  }
}

extern "C" void kernel_launch(void* const* d_in, const int* in_sizes, int n_in,
                              void* d_out, int out_size, void* d_ws, size_t ws_size,
                              hipStream_t stream) {
  const float* x     = (const float*)d_in[0];
  const float* ln1w  = (const float*)d_in[1];
  const float* ln1b  = (const float*)d_in[2];
  const float* W_in  = (const float*)d_in[3];
  const float* convw = (const float*)d_in[4];
  const float* convb = (const float*)d_in[5];
  const float* W_x   = (const float*)d_in[6];
  const float* W_dt  = (const float*)d_in[7];
  const float* b_dt  = (const float*)d_in[8];
  const float* A_log = (const float*)d_in[9];
  const float* Dskip = (const float*)d_in[10];
  const float* W_out = (const float*)d_in[11];
  const float* ln2w  = (const float*)d_in[12];
  const float* ln2b  = (const float*)d_in[13];
  const float* W1    = (const float*)d_in[14];
  const float* b1    = (const float*)d_in[15];
  const float* W2    = (const float*)d_in[16];
  const float* b2    = (const float*)d_in[17];
  float* out = (float*)d_out;

  uint8_t* ws = (uint8_t*)d_ws;
  size_t off = 0;
  auto alloc = [&](size_t bytes) { void* p = ws + off; off = (off + bytes + 255) & ~(size_t)255; return p; };

  bf16*  wInb  = (bf16*)alloc(3072ull * 768 * 2);
  bf16*  wXb   = (bf16*)alloc(128ull * 1536 * 2);
  bf16*  wDtb  = (bf16*)alloc(1536ull * 64 * 2);
  bf16*  wOutb = (bf16*)alloc(768ull * 1536 * 2);
  bf16*  w1b   = (bf16*)alloc(3072ull * 768 * 2);
  bf16*  w2b   = (bf16*)alloc(768ull * 3072 * 2);
  bf16*  xln   = (bf16*)alloc(8192ull * 768 * 2);    // reused as m_ln
  bf16*  xz    = (bf16*)alloc(8192ull * 3072 * 2);   // reused as a1
  bf16*  u     = (bf16*)alloc(8192ull * 1536 * 2);
  float* xdblf = (float*)alloc(8192ull * 128 * 4);
  bf16*  xdblb = (bf16*)alloc(8192ull * 128 * 2);
  bf16*  dtb   = (bf16*)alloc(8192ull * 1536 * 2);
  bf16*  ygate = (bf16*)alloc(8192ull * 1536 * 2);
  float* hbuf  = (float*)alloc(8192ull * 768 * 4);
  (void)ws_size; (void)in_sizes; (void)n_in; (void)out_size;

  // weights -> bf16 (re-done every call; harness re-poisons ws)
  cast_pad<<<dim3(3, 3072),  256, 0, stream>>>(W_in,  wInb,  768,  3072, 768);
  cast_pad<<<dim3(6, 128),   256, 0, stream>>>(W_x,   wXb,   1536, 80,   1536);
  cast_pad<<<dim3(1, 1536),  256, 0, stream>>>(W_dt,  wDtb,  64,   1536, 48);
  cast_pad<<<dim3(6, 768),   256, 0, stream>>>(W_out, wOutb, 1536, 768,  1536);
  cast_pad<<<dim3(3, 3072),  256, 0, stream>>>(W1,    w1b,   768,  3072, 768);
  cast_pad<<<dim3(12, 768),  256, 0, stream>>>(W2,    w2b,   3072, 768,  3072);

  ln_cast<<<8192, 256, 0, stream>>>(x, ln1w, ln1b, xln);

  // xz = ln(x) @ W_in^T
  gemm_bt<0><<<dim3(24, 64), 256, 0, stream>>>(xln, wInb, 3072, 768, 768, 768, xz, nullptr, nullptr, nullptr);
  conv_silu<<<dim3(6, 8192), 256, 0, stream>>>(xz, convw, convb, u);
  // x_dbl = u @ W_x^T (N padded to 128)
  gemm_bt<1><<<dim3(1, 64), 256, 0, stream>>>(u, wXb, 128, 1536, 1536, 1536, xdblf, xdblb, nullptr, nullptr);
  // dt = softplus(x_dbl[:, :48] @ W_dt^T + b_dt)  (K padded to 64, W_dt cols 48..63 zero)
  gemm_bt<2><<<dim3(12, 64), 256, 0, stream>>>(xdblb, wDtb, 1536, 64, 128, 64, dtb, nullptr, b_dt, nullptr);
  scan_fuse<<<384, 256, 0, stream>>>(dtb, u, xz, xdblf, A_log, Dskip, ygate);
  // h = x + y @ W_out^T
  gemm_bt<3><<<dim3(6, 64), 256, 0, stream>>>(ygate, wOutb, 768, 1536, 1536, 1536, hbuf, nullptr, nullptr, x);
  ln_cast<<<8192, 256, 0, stream>>>(hbuf, ln2w, ln2b, xln);
  // a1 = relu(m_ln @ W1^T + b1)
  gemm_bt<4><<<dim3(24, 64), 256, 0, stream>>>(xln, w1b, 3072, 768, 768, 768, xz, nullptr, b1, nullptr);
  // out = h + a1 @ W2^T + b2
  gemm_bt<5><<<dim3(6, 64), 256, 0, stream>>>(xz, w2b, 768, 3072, 3072, 3072, out, nullptr, b2, hbuf);
}

// Round 3
// 684.651 us; speedup vs baseline: 1.6207x; 1.6207x over previous
//
#include <hip/hip_runtime.h>
#include <cstdint>

typedef __bf16 bf16;
typedef __bf16 bf16x8 __attribute__((ext_vector_type(8)));
typedef float  f32x4  __attribute__((ext_vector_type(4)));

#define NCH 32   // scan chunks
#define CT  64   // chunk length (NCH*CT == 2048)

__device__ __forceinline__ void g2l16(const bf16* g, bf16* l) {
  __builtin_amdgcn_global_load_lds(
      (const __attribute__((address_space(1))) unsigned int*)g,
      (__attribute__((address_space(3))) unsigned int*)l, 16, 0, 0);
}

// ---------- cast fp32 weights -> bf16, with zero padding ----------
__global__ __launch_bounds__(256) void cast_pad(const float* __restrict__ src, bf16* __restrict__ dst,
                                                int cd, int rs, int cs) {
  int c = blockIdx.x * 256 + threadIdx.x;
  int r = blockIdx.y;
  if (c >= cd) return;
  float v = (r < rs && c < cs) ? src[(size_t)r * cs + c] : 0.f;
  dst[(size_t)r * cd + c] = (bf16)v;
}

// ---------- layernorm (D=768) + cast to bf16 ----------
__global__ __launch_bounds__(256) void ln_cast(const float* __restrict__ x, const float* __restrict__ w,
                                               const float* __restrict__ b, bf16* __restrict__ out) {
  const int row = blockIdx.x;
  const int tid = threadIdx.x;
  const float* xr = x + (size_t)row * 768;
  float v0 = xr[tid], v1 = xr[tid + 256], v2 = xr[tid + 512];
  float s = v0 + v1 + v2;
  __shared__ float red[8];
  #pragma unroll
  for (int o = 32; o; o >>= 1) s += __shfl_down(s, o);
  if ((tid & 63) == 0) red[tid >> 6] = s;
  __syncthreads();
  float mean = (red[0] + red[1] + red[2] + red[3]) * (1.f / 768.f);
  float d0 = v0 - mean, d1 = v1 - mean, d2 = v2 - mean;
  float q = d0 * d0 + d1 * d1 + d2 * d2;
  #pragma unroll
  for (int o = 32; o; o >>= 1) q += __shfl_down(q, o);
  if ((tid & 63) == 0) red[4 + (tid >> 6)] = q;
  __syncthreads();
  float var = (red[4] + red[5] + red[6] + red[7]) * (1.f / 768.f);
  float inv = rsqrtf(var + 1e-5f);
  bf16* orow = out + (size_t)row * 768;
  orow[tid]       = (bf16)(d0 * inv * w[tid]       + b[tid]);
  orow[tid + 256] = (bf16)(d1 * inv * w[tid + 256] + b[tid + 256]);
  orow[tid + 512] = (bf16)(d2 * inv * w[tid + 512] + b[tid + 512]);
}

// ---------- causal depthwise conv (width 4) + SiLU ----------
__global__ __launch_bounds__(256) void conv_silu(const bf16* __restrict__ xz, const float* __restrict__ cw,
                                                 const float* __restrict__ cb, bf16* __restrict__ u) {
  int c = blockIdx.x * 256 + threadIdx.x;   // 0..1535
  int r = blockIdx.y;                        // 0..8191 (b*2048+t)
  int t = r & 2047;
  const float4 wv = ((const float4*)cw)[c];
  float acc = cb[c];
  const bf16* col = xz + c;
  if (t >= 3) {
    acc += (float)col[(size_t)(r - 3) * 3072] * wv.x;
    acc += (float)col[(size_t)(r - 2) * 3072] * wv.y;
    acc += (float)col[(size_t)(r - 1) * 3072] * wv.z;
  } else {
    if (t >= 2) acc += (float)col[(size_t)(r - 2) * 3072] * wv.y;
    if (t >= 1) acc += (float)col[(size_t)(r - 1) * 3072] * wv.z;
  }
  acc += (float)col[(size_t)r * 3072] * wv.w;
  float sg = 1.f / (1.f + __expf(-acc));
  u[(size_t)r * 1536 + c] = (bf16)(acc * sg);
}

// ---------- MFMA GEMM: C(M,N) = A(M,K) @ B(N,K)^T, 128x128 tile, BK=32 ----------
template<int EPI>
__global__ __launch_bounds__(256) void gemm_bt(
    const bf16* __restrict__ A, const bf16* __restrict__ B,
    int N, int K, int lda, int ldb,
    void* __restrict__ C0, void* __restrict__ C1,
    const float* __restrict__ aux, const float* __restrict__ aux2)
{
  __shared__ alignas(16) bf16 As[4096];
  __shared__ alignas(16) bf16 Bs[4096];
  const int tid = threadIdx.x;
  const int w = tid >> 6, l = tid & 63;
  const int m0 = blockIdx.y * 128, n0 = blockIdx.x * 128;
  const int wr = (w >> 1) * 64, wc = (w & 1) * 64;

  const int srow = tid >> 2;
  const int scol = (tid & 3) * 8;
  const bf16* ag  = A + (size_t)(m0 + srow) * lda + scol;
  const bf16* ag2 = A + (size_t)(m0 + 64 + srow) * lda + scol;
  const bf16* bg  = B + (size_t)(n0 + srow) * ldb + scol;
  const bf16* bg2 = B + (size_t)(n0 + 64 + srow) * ldb + scol;
  bf16* lA  = &As[w * 512];
  bf16* lA2 = &As[2048 + w * 512];
  bf16* lB  = &Bs[w * 512];
  bf16* lB2 = &Bs[2048 + w * 512];

  f32x4 acc[4][4] = {};
  const int fr = l & 15, kb = (l >> 4) * 8;

  for (int k0 = 0; k0 < K; k0 += 32) {
    g2l16(ag  + k0, lA);
    g2l16(ag2 + k0, lA2);
    g2l16(bg  + k0, lB);
    g2l16(bg2 + k0, lB2);
    __syncthreads();
    bf16x8 af[4], bfr[4];
    #pragma unroll
    for (int i = 0; i < 4; ++i) {
      af[i]  = *(const bf16x8*)&As[(wr + i * 16 + fr) * 32 + kb];
      bfr[i] = *(const bf16x8*)&Bs[(wc + i * 16 + fr) * 32 + kb];
    }
    #pragma unroll
    for (int i = 0; i < 4; ++i)
      #pragma unroll
      for (int j = 0; j < 4; ++j)
        acc[i][j] = __builtin_amdgcn_mfma_f32_16x16x32_bf16(af[i], bfr[j], acc[i][j], 0, 0, 0);
    __syncthreads();
  }

  const int fq = (l >> 4) * 4;
  #pragma unroll
  for (int i = 0; i < 4; ++i) {
    #pragma unroll
    for (int j = 0; j < 4; ++j) {
      int row = m0 + wr + i * 16 + fq;
      int col = n0 + wc + j * 16 + fr;
      f32x4 v = acc[i][j];
      #pragma unroll
      for (int jj = 0; jj < 4; ++jj) {
        size_t idx = (size_t)(row + jj) * N + col;
        float val = v[jj];
        if constexpr (EPI == 0) {
          ((bf16*)C0)[idx] = (bf16)val;
        } else if constexpr (EPI == 1) {
          ((float*)C0)[idx] = val;
          ((bf16*)C1)[idx] = (bf16)val;
        } else if constexpr (EPI == 2) {
          float xv = val + aux[col];
          float sp = (xv > 20.f) ? xv : log1pf(__expf(xv));
          ((bf16*)C0)[idx] = (bf16)sp;
        } else if constexpr (EPI == 3) {
          ((float*)C0)[idx] = val + aux2[idx];
        } else if constexpr (EPI == 4) {
          float xv = val + aux[col];
          ((bf16*)C0)[idx] = (bf16)(xv > 0.f ? xv : 0.f);
        } else if constexpr (EPI == 5) {
          ((float*)C0)[idx] = val + aux[col] + aux2[idx];
        }
      }
    }
  }
}

// ---------- chunked parallel scan ----------
// pass1: per (b, chunk, 256-ch group): local scan from h=0 -> P (decay product), hend
__global__ __launch_bounds__(256) void scan_pass1(
    const bf16* __restrict__ dtb, const bf16* __restrict__ ub,
    const float* __restrict__ xdbl, const float* __restrict__ A_log,
    float* __restrict__ Pp, float* __restrict__ hend)
{
  __shared__ float Bs[CT * 16];
  const int tid = threadIdx.x;
  const int cg = blockIdx.x, k = blockIdx.y, b = blockIdx.z;
  const int c = cg * 256 + tid;
  const size_t rowbase = (size_t)b * 2048 + (size_t)k * CT;

  for (int i = tid; i < CT * 16; i += 256) {
    int tr = i >> 4, q = i & 15;
    Bs[i] = xdbl[(rowbase + tr) * 128 + 48 + q];
  }
  float al2[16];
  {
    const float4* ap = (const float4*)&A_log[c * 16];
    #pragma unroll
    for (int qq = 0; qq < 4; ++qq) {
      float4 a = ap[qq];
      al2[qq*4+0] = -__expf(a.x) * 1.44269504f;
      al2[qq*4+1] = -__expf(a.y) * 1.44269504f;
      al2[qq*4+2] = -__expf(a.z) * 1.44269504f;
      al2[qq*4+3] = -__expf(a.w) * 1.44269504f;
    }
  }
  __syncthreads();

  float h[16];
  #pragma unroll
  for (int n = 0; n < 16; ++n) h[n] = 0.f;
  float sdt = 0.f;

  for (int t8 = 0; t8 < CT / 8; ++t8) {
    float dv[8], xv[8];
    #pragma unroll
    for (int tt = 0; tt < 8; ++tt) {
      size_t row = rowbase + t8 * 8 + tt;
      float d = (float)dtb[row * 1536 + c];
      dv[tt] = d;
      xv[tt] = d * (float)ub[row * 1536 + c];
    }
    #pragma unroll
    for (int tt = 0; tt < 8; ++tt) {
      float d = dv[tt], x = xv[tt];
      sdt += d;
      float Bv[16];
      const float4* bp = (const float4*)&Bs[(t8 * 8 + tt) * 16];
      ((float4*)Bv)[0] = bp[0]; ((float4*)Bv)[1] = bp[1];
      ((float4*)Bv)[2] = bp[2]; ((float4*)Bv)[3] = bp[3];
      #pragma unroll
      for (int n = 0; n < 16; ++n) {
        float e = exp2f(d * al2[n]);
        h[n] = h[n] * e + x * Bv[n];
      }
    }
  }
  size_t off = ((size_t)(b * NCH + k) * 1536 + c) * 16;
  float P[16];
  #pragma unroll
  for (int n = 0; n < 16; ++n) P[n] = exp2f(al2[n] * sdt);
  #pragma unroll
  for (int qq = 0; qq < 4; ++qq) {
    ((float4*)&Pp[off])[qq]   = ((float4*)P)[qq];
    ((float4*)&hend[off])[qq] = ((float4*)h)[qq];
  }
}

// pass2: sequential combine over chunks; hstart[k] = state entering chunk k
__global__ __launch_bounds__(256) void scan_pass2(
    const float* __restrict__ Pp, const float* __restrict__ hend, float* __restrict__ hstart)
{
  int t = blockIdx.x * 256 + threadIdx.x;   // 0..98303
  int b = t / 24576;
  int r = t - b * 24576;                    // c*16+n
  size_t base = (size_t)b * (NCH * 24576) + r;
  float hs = 0.f;
  for (int k = 0; k < NCH; ++k) {
    size_t off = base + (size_t)k * 24576;
    hstart[off] = hs;
    hs = Pp[off] * hs + hend[off];
  }
}

// pass3: re-scan with true start state; fused y-reduce + D_skip + silu(z) gating
__global__ __launch_bounds__(256) void scan_pass3(
    const bf16* __restrict__ dtb, const bf16* __restrict__ ub, const bf16* __restrict__ xzb,
    const float* __restrict__ xdbl, const float* __restrict__ A_log, const float* __restrict__ Dskip,
    const float* __restrict__ hstart, bf16* __restrict__ yg)
{
  __shared__ float BCs[CT * 32];
  const int tid = threadIdx.x;
  const int cg = blockIdx.x, k = blockIdx.y, b = blockIdx.z;
  const int c = cg * 256 + tid;
  const size_t rowbase = (size_t)b * 2048 + (size_t)k * CT;

  for (int i = tid; i < CT * 32; i += 256) {
    int tr = i >> 5, q = i & 31;
    BCs[i] = xdbl[(rowbase + tr) * 128 + 48 + q];
  }
  float al2[16];
  {
    const float4* ap = (const float4*)&A_log[c * 16];
    #pragma unroll
    for (int qq = 0; qq < 4; ++qq) {
      float4 a = ap[qq];
      al2[qq*4+0] = -__expf(a.x) * 1.44269504f;
      al2[qq*4+1] = -__expf(a.y) * 1.44269504f;
      al2[qq*4+2] = -__expf(a.z) * 1.44269504f;
      al2[qq*4+3] = -__expf(a.w) * 1.44269504f;
    }
  }
  const float dsk = Dskip[c];
  float h[16];
  {
    size_t off = ((size_t)(b * NCH + k) * 1536 + c) * 16;
    #pragma unroll
    for (int qq = 0; qq < 4; ++qq) ((float4*)h)[qq] = ((const float4*)&hstart[off])[qq];
  }
  __syncthreads();

  for (int t8 = 0; t8 < CT / 8; ++t8) {
    float dv[8], uv[8], gv[8];
    #pragma unroll
    for (int tt = 0; tt < 8; ++tt) {
      size_t row = rowbase + t8 * 8 + tt;
      dv[tt] = (float)dtb[row * 1536 + c];
      uv[tt] = (float)ub[row * 1536 + c];
      float zv = (float)xzb[row * 3072 + 1536 + c];
      gv[tt] = zv / (1.f + __expf(-zv));
    }
    #pragma unroll
    for (int tt = 0; tt < 8; ++tt) {
      float d = dv[tt], x = d * uv[tt];
      float BC[32];
      const float4* bp = (const float4*)&BCs[(t8 * 8 + tt) * 32];
      #pragma unroll
      for (int qq = 0; qq < 8; ++qq) ((float4*)BC)[qq] = bp[qq];
      float y = 0.f;
      #pragma unroll
      for (int n = 0; n < 16; ++n) {
        float e = exp2f(d * al2[n]);
        h[n] = h[n] * e + x * BC[n];
        y += h[n] * BC[16 + n];
      }
      size_t row = rowbase + t8 * 8 + tt;
      yg[row * 1536 + c] = (bf16)((y + uv[tt] * dsk) * gv[tt]);
    }
  }
}

extern "C" void kernel_launch(void* const* d_in, const int* in_sizes, int n_in,
                              void* d_out, int out_size, void* d_ws, size_t ws_size,
                              hipStream_t stream) {
  const float* x     = (const float*)d_in[0];
  const float* ln1w  = (const float*)d_in[1];
  const float* ln1b  = (const float*)d_in[2];
  const float* W_in  = (const float*)d_in[3];
  const float* convw = (const float*)d_in[4];
  const float* convb = (const float*)d_in[5];
  const float* W_x   = (const float*)d_in[6];
  const float* W_dt  = (const float*)d_in[7];
  const float* b_dt  = (const float*)d_in[8];
  const float* A_log = (const float*)d_in[9];
  const float* Dskip = (const float*)d_in[10];
  const float* W_out = (const float*)d_in[11];
  const float* ln2w  = (const float*)d_in[12];
  const float* ln2b  = (const float*)d_in[13];
  const float* W1    = (const float*)d_in[14];
  const float* b1    = (const float*)d_in[15];
  const float* W2    = (const float*)d_in[16];
  const float* b2    = (const float*)d_in[17];
  float* out = (float*)d_out;

  uint8_t* ws = (uint8_t*)d_ws;
  size_t off = 0;
  auto alloc = [&](size_t bytes) { void* p = ws + off; off = (off + bytes + 255) & ~(size_t)255; return p; };

  bf16*  wInb  = (bf16*)alloc(3072ull * 768 * 2);
  bf16*  wXb   = (bf16*)alloc(128ull * 1536 * 2);
  bf16*  wDtb  = (bf16*)alloc(1536ull * 64 * 2);
  bf16*  wOutb = (bf16*)alloc(768ull * 1536 * 2);
  bf16*  w1b   = (bf16*)alloc(3072ull * 768 * 2);
  bf16*  w2b   = (bf16*)alloc(768ull * 3072 * 2);
  bf16*  xln   = (bf16*)alloc(8192ull * 768 * 2);    // reused as m_ln; P overlay during scan
  bf16*  xz    = (bf16*)alloc(8192ull * 3072 * 2);   // reused as a1
  bf16*  u     = (bf16*)alloc(8192ull * 1536 * 2);
  float* xdblf = (float*)alloc(8192ull * 128 * 4);
  bf16*  xdblb = (bf16*)alloc(8192ull * 128 * 2);
  bf16*  dtb   = (bf16*)alloc(8192ull * 1536 * 2);
  bf16*  ygate = (bf16*)alloc(8192ull * 1536 * 2);
  float* hbuf  = (float*)alloc(8192ull * 768 * 4);   // hstart overlay during scan
  float* hendb = (float*)alloc(4ull * NCH * 1536 * 16 * 4);
  (void)ws_size; (void)in_sizes; (void)n_in; (void)out_size;

  // scan scratch overlays (dead ranges during the scan phase):
  float* Pbuf    = (float*)xln;   // 12.58 MB == exactly P size
  float* hstartb = (float*)hbuf;  // 12.58 MB of 25.2 MB

  cast_pad<<<dim3(3, 3072),  256, 0, stream>>>(W_in,  wInb,  768,  3072, 768);
  cast_pad<<<dim3(6, 128),   256, 0, stream>>>(W_x,   wXb,   1536, 80,   1536);
  cast_pad<<<dim3(1, 1536),  256, 0, stream>>>(W_dt,  wDtb,  64,   1536, 48);
  cast_pad<<<dim3(6, 768),   256, 0, stream>>>(W_out, wOutb, 1536, 768,  1536);
  cast_pad<<<dim3(3, 3072),  256, 0, stream>>>(W1,    w1b,   768,  3072, 768);
  cast_pad<<<dim3(12, 768),  256, 0, stream>>>(W2,    w2b,   3072, 768,  3072);

  ln_cast<<<8192, 256, 0, stream>>>(x, ln1w, ln1b, xln);

  // xz = ln(x) @ W_in^T
  gemm_bt<0><<<dim3(24, 64), 256, 0, stream>>>(xln, wInb, 3072, 768, 768, 768, xz, nullptr, nullptr, nullptr);
  conv_silu<<<dim3(6, 8192), 256, 0, stream>>>(xz, convw, convb, u);
  // x_dbl = u @ W_x^T (N padded to 128)
  gemm_bt<1><<<dim3(1, 64), 256, 0, stream>>>(u, wXb, 128, 1536, 1536, 1536, xdblf, xdblb, nullptr, nullptr);
  // dt = softplus(x_dbl[:, :48] @ W_dt^T + b_dt)
  gemm_bt<2><<<dim3(12, 64), 256, 0, stream>>>(xdblb, wDtb, 1536, 64, 128, 64, dtb, nullptr, b_dt, nullptr);
  // chunked scan (xln free here; hbuf written only after)
  scan_pass1<<<dim3(6, NCH, 4), 256, 0, stream>>>(dtb, u, xdblf, A_log, Pbuf, hendb);
  scan_pass2<<<384, 256, 0, stream>>>(Pbuf, hendb, hstartb);
  scan_pass3<<<dim3(6, NCH, 4), 256, 0, stream>>>(dtb, u, xz, xdblf, A_log, Dskip, hstartb, ygate);
  // h = x + y @ W_out^T
  gemm_bt<3><<<dim3(6, 64), 256, 0, stream>>>(ygate, wOutb, 768, 1536, 1536, 1536, hbuf, nullptr, nullptr, x);
  ln_cast<<<8192, 256, 0, stream>>>(hbuf, ln2w, ln2b, xln);
  // a1 = relu(m_ln @ W1^T + b1)
  gemm_bt<4><<<dim3(24, 64), 256, 0, stream>>>(xln, w1b, 3072, 768, 768, 768, xz, nullptr, b1, nullptr);
  // out = h + a1 @ W2^T + b2
  gemm_bt<5><<<dim3(6, 64), 256, 0, stream>>>(xz, w2b, 768, 3072, 3072, 3072, out, nullptr, b2, hbuf);
}

// Round 4
// 652.727 us; speedup vs baseline: 1.7000x; 1.0489x over previous
//
#include <hip/hip_runtime.h>
#include <cstdint>

typedef __bf16 bf16;
typedef __bf16 bf16x8 __attribute__((ext_vector_type(8)));
typedef float  f32x4  __attribute__((ext_vector_type(4)));

#define NCH 32   // scan chunks
#define CT  64   // chunk length (NCH*CT == 2048)

__device__ __forceinline__ void g2l16(const bf16* g, bf16* l) {
  __builtin_amdgcn_global_load_lds(
      (const __attribute__((address_space(1))) unsigned int*)g,
      (__attribute__((address_space(3))) unsigned int*)l, 16, 0, 0);
}

// ---------- cast fp32 weights -> bf16, with zero padding ----------
__global__ __launch_bounds__(256) void cast_pad(const float* __restrict__ src, bf16* __restrict__ dst,
                                                int cd, int rs, int cs) {
  int c = blockIdx.x * 256 + threadIdx.x;
  int r = blockIdx.y;
  if (c >= cd) return;
  float v = (r < rs && c < cs) ? src[(size_t)r * cs + c] : 0.f;
  dst[(size_t)r * cd + c] = (bf16)v;
}

// ---------- layernorm (D=768) + cast to bf16 ----------
__global__ __launch_bounds__(256) void ln_cast(const float* __restrict__ x, const float* __restrict__ w,
                                               const float* __restrict__ b, bf16* __restrict__ out) {
  const int row = blockIdx.x;
  const int tid = threadIdx.x;
  const float* xr = x + (size_t)row * 768;
  float v0 = xr[tid], v1 = xr[tid + 256], v2 = xr[tid + 512];
  float s = v0 + v1 + v2;
  __shared__ float red[8];
  #pragma unroll
  for (int o = 32; o; o >>= 1) s += __shfl_down(s, o);
  if ((tid & 63) == 0) red[tid >> 6] = s;
  __syncthreads();
  float mean = (red[0] + red[1] + red[2] + red[3]) * (1.f / 768.f);
  float d0 = v0 - mean, d1 = v1 - mean, d2 = v2 - mean;
  float q = d0 * d0 + d1 * d1 + d2 * d2;
  #pragma unroll
  for (int o = 32; o; o >>= 1) q += __shfl_down(q, o);
  if ((tid & 63) == 0) red[4 + (tid >> 6)] = q;
  __syncthreads();
  float var = (red[4] + red[5] + red[6] + red[7]) * (1.f / 768.f);
  float inv = rsqrtf(var + 1e-5f);
  bf16* orow = out + (size_t)row * 768;
  orow[tid]       = (bf16)(d0 * inv * w[tid]       + b[tid]);
  orow[tid + 256] = (bf16)(d1 * inv * w[tid + 256] + b[tid + 256]);
  orow[tid + 512] = (bf16)(d2 * inv * w[tid + 512] + b[tid + 512]);
}

// ---------- causal depthwise conv (width 4) + SiLU ----------
__global__ __launch_bounds__(256) void conv_silu(const bf16* __restrict__ xz, const float* __restrict__ cw,
                                                 const float* __restrict__ cb, bf16* __restrict__ u) {
  int c = blockIdx.x * 256 + threadIdx.x;   // 0..1535
  int r = blockIdx.y;                        // 0..8191 (b*2048+t)
  int t = r & 2047;
  const float4 wv = ((const float4*)cw)[c];
  float acc = cb[c];
  const bf16* col = xz + c;
  if (t >= 3) {
    acc += (float)col[(size_t)(r - 3) * 3072] * wv.x;
    acc += (float)col[(size_t)(r - 2) * 3072] * wv.y;
    acc += (float)col[(size_t)(r - 1) * 3072] * wv.z;
  } else {
    if (t >= 2) acc += (float)col[(size_t)(r - 2) * 3072] * wv.y;
    if (t >= 1) acc += (float)col[(size_t)(r - 1) * 3072] * wv.z;
  }
  acc += (float)col[(size_t)r * 3072] * wv.w;
  float sg = 1.f / (1.f + __expf(-acc));
  u[(size_t)r * 1536 + c] = (bf16)(acc * sg);
}

// ---------- MFMA GEMM: C(M,N) = A(M,K) @ B(N,K)^T, 128x128 tile, BK=32 ----------
// 2-phase dbuf pipeline + XCD-bijective block swizzle + LDS slot-XOR swizzle
// (linear global_load_lds dest, pre-swizzled global source, swizzled ds_read).
template<int EPI>
__global__ __launch_bounds__(256) void gemm_bt(
    const bf16* __restrict__ A, const bf16* __restrict__ B,
    int N, int K, int lda, int ldb,
    void* __restrict__ C0, void* __restrict__ C1,
    const float* __restrict__ aux, const float* __restrict__ aux2)
{
  __shared__ alignas(16) bf16 As[2][4096];
  __shared__ alignas(16) bf16 Bs[2][4096];
  const int tid = threadIdx.x;
  const int w = tid >> 6, l = tid & 63;

  // XCD-aware bijective swizzle (all launch grids have nwg % 8 == 0):
  // XCD k executes a contiguous chunk of M-panels -> A-tiles stay L2-resident.
  const int nwg = gridDim.x * gridDim.y;
  const int orig = blockIdx.x + gridDim.x * blockIdx.y;
  const int n8 = nwg >> 3;
  const int sw = (orig & 7) * n8 + (orig >> 3);
  const int m0 = (sw / gridDim.x) * 128;
  const int n0 = (sw % gridDim.x) * 128;

  const int wr = (w >> 1) * 64, wc = (w & 1) * 64;

  const int srow = tid >> 2;                    // LDS row this lane stages (0..63)
  const int slot = tid & 3;                     // 16B slot within 64B row
  const int scol = (slot ^ (srow & 3)) * 8;     // pre-swizzled global column (elements)
  const bf16* ag  = A + (size_t)(m0 + srow) * lda + scol;
  const bf16* ag2 = A + (size_t)(m0 + 64 + srow) * lda + scol;
  const bf16* bg  = B + (size_t)(n0 + srow) * ldb + scol;
  const bf16* bg2 = B + (size_t)(n0 + 64 + srow) * ldb + scol;

  f32x4 acc[4][4] = {};
  const int fr = l & 15, kb = (l >> 4) * 8;

  // prologue: stage first K-tile into buf 0
  g2l16(ag,  &As[0][w * 512]);
  g2l16(ag2, &As[0][2048 + w * 512]);
  g2l16(bg,  &Bs[0][w * 512]);
  g2l16(bg2, &Bs[0][2048 + w * 512]);
  __syncthreads();

  int cur = 0;
  for (int k0 = 0; k0 < K; k0 += 32) {
    if (k0 + 32 < K) {   // prefetch next K-tile into the other buffer
      int nx = cur ^ 1, kn = k0 + 32;
      g2l16(ag  + kn, &As[nx][w * 512]);
      g2l16(ag2 + kn, &As[nx][2048 + w * 512]);
      g2l16(bg  + kn, &Bs[nx][w * 512]);
      g2l16(bg2 + kn, &Bs[nx][2048 + w * 512]);
    }
    bf16x8 af[4], bfr[4];
    #pragma unroll
    for (int i = 0; i < 4; ++i) {
      const int ra = wr + i * 16 + fr;
      const int rb = wc + i * 16 + fr;
      af[i]  = *(const bf16x8*)&As[cur][ra * 32 + (kb ^ ((ra & 3) << 3))];
      bfr[i] = *(const bf16x8*)&Bs[cur][rb * 32 + (kb ^ ((rb & 3) << 3))];
    }
    #pragma unroll
    for (int i = 0; i < 4; ++i)
      #pragma unroll
      for (int j = 0; j < 4; ++j)
        acc[i][j] = __builtin_amdgcn_mfma_f32_16x16x32_bf16(af[i], bfr[j], acc[i][j], 0, 0, 0);
    __syncthreads();   // drains prefetch (vmcnt) + all ds_reads of buf[cur]
    cur ^= 1;
  }

  const int fq = (l >> 4) * 4;
  #pragma unroll
  for (int i = 0; i < 4; ++i) {
    #pragma unroll
    for (int j = 0; j < 4; ++j) {
      int row = m0 + wr + i * 16 + fq;
      int col = n0 + wc + j * 16 + fr;
      f32x4 v = acc[i][j];
      #pragma unroll
      for (int jj = 0; jj < 4; ++jj) {
        size_t idx = (size_t)(row + jj) * N + col;
        float val = v[jj];
        if constexpr (EPI == 0) {
          ((bf16*)C0)[idx] = (bf16)val;
        } else if constexpr (EPI == 1) {
          ((float*)C0)[idx] = val;
          ((bf16*)C1)[idx] = (bf16)val;
        } else if constexpr (EPI == 2) {
          float xv = val + aux[col];
          float sp = (xv > 20.f) ? xv : log1pf(__expf(xv));
          ((bf16*)C0)[idx] = (bf16)sp;
        } else if constexpr (EPI == 3) {
          ((float*)C0)[idx] = val + aux2[idx];
        } else if constexpr (EPI == 4) {
          float xv = val + aux[col];
          ((bf16*)C0)[idx] = (bf16)(xv > 0.f ? xv : 0.f);
        } else if constexpr (EPI == 5) {
          ((float*)C0)[idx] = val + aux[col] + aux2[idx];
        }
      }
    }
  }
}

// ---------- chunked parallel scan ----------
__global__ __launch_bounds__(256) void scan_pass1(
    const bf16* __restrict__ dtb, const bf16* __restrict__ ub,
    const float* __restrict__ xdbl, const float* __restrict__ A_log,
    float* __restrict__ Pp, float* __restrict__ hend)
{
  __shared__ float Bs[CT * 16];
  const int tid = threadIdx.x;
  const int cg = blockIdx.x, k = blockIdx.y, b = blockIdx.z;
  const int c = cg * 256 + tid;
  const size_t rowbase = (size_t)b * 2048 + (size_t)k * CT;

  for (int i = tid; i < CT * 16; i += 256) {
    int tr = i >> 4, q = i & 15;
    Bs[i] = xdbl[(rowbase + tr) * 128 + 48 + q];
  }
  float al2[16];
  {
    const float4* ap = (const float4*)&A_log[c * 16];
    #pragma unroll
    for (int qq = 0; qq < 4; ++qq) {
      float4 a = ap[qq];
      al2[qq*4+0] = -__expf(a.x) * 1.44269504f;
      al2[qq*4+1] = -__expf(a.y) * 1.44269504f;
      al2[qq*4+2] = -__expf(a.z) * 1.44269504f;
      al2[qq*4+3] = -__expf(a.w) * 1.44269504f;
    }
  }
  __syncthreads();

  float h[16];
  #pragma unroll
  for (int n = 0; n < 16; ++n) h[n] = 0.f;
  float sdt = 0.f;

  for (int t8 = 0; t8 < CT / 8; ++t8) {
    float dv[8], xv[8];
    #pragma unroll
    for (int tt = 0; tt < 8; ++tt) {
      size_t row = rowbase + t8 * 8 + tt;
      float d = (float)dtb[row * 1536 + c];
      dv[tt] = d;
      xv[tt] = d * (float)ub[row * 1536 + c];
    }
    #pragma unroll
    for (int tt = 0; tt < 8; ++tt) {
      float d = dv[tt], x = xv[tt];
      sdt += d;
      float Bv[16];
      const float4* bp = (const float4*)&Bs[(t8 * 8 + tt) * 16];
      ((float4*)Bv)[0] = bp[0]; ((float4*)Bv)[1] = bp[1];
      ((float4*)Bv)[2] = bp[2]; ((float4*)Bv)[3] = bp[3];
      #pragma unroll
      for (int n = 0; n < 16; ++n) {
        float e = exp2f(d * al2[n]);
        h[n] = h[n] * e + x * Bv[n];
      }
    }
  }
  size_t off = ((size_t)(b * NCH + k) * 1536 + c) * 16;
  float P[16];
  #pragma unroll
  for (int n = 0; n < 16; ++n) P[n] = exp2f(al2[n] * sdt);
  #pragma unroll
  for (int qq = 0; qq < 4; ++qq) {
    ((float4*)&Pp[off])[qq]   = ((float4*)P)[qq];
    ((float4*)&hend[off])[qq] = ((float4*)h)[qq];
  }
}

__global__ __launch_bounds__(256) void scan_pass2(
    const float* __restrict__ Pp, const float* __restrict__ hend, float* __restrict__ hstart)
{
  int t = blockIdx.x * 256 + threadIdx.x;   // 0..98303
  int b = t / 24576;
  int r = t - b * 24576;                    // c*16+n
  size_t base = (size_t)b * (NCH * 24576) + r;
  float hs = 0.f;
  for (int k = 0; k < NCH; ++k) {
    size_t off = base + (size_t)k * 24576;
    hstart[off] = hs;
    hs = Pp[off] * hs + hend[off];
  }
}

__global__ __launch_bounds__(256) void scan_pass3(
    const bf16* __restrict__ dtb, const bf16* __restrict__ ub, const bf16* __restrict__ xzb,
    const float* __restrict__ xdbl, const float* __restrict__ A_log, const float* __restrict__ Dskip,
    const float* __restrict__ hstart, bf16* __restrict__ yg)
{
  __shared__ float BCs[CT * 32];
  const int tid = threadIdx.x;
  const int cg = blockIdx.x, k = blockIdx.y, b = blockIdx.z;
  const int c = cg * 256 + tid;
  const size_t rowbase = (size_t)b * 2048 + (size_t)k * CT;

  for (int i = tid; i < CT * 32; i += 256) {
    int tr = i >> 5, q = i & 31;
    BCs[i] = xdbl[(rowbase + tr) * 128 + 48 + q];
  }
  float al2[16];
  {
    const float4* ap = (const float4*)&A_log[c * 16];
    #pragma unroll
    for (int qq = 0; qq < 4; ++qq) {
      float4 a = ap[qq];
      al2[qq*4+0] = -__expf(a.x) * 1.44269504f;
      al2[qq*4+1] = -__expf(a.y) * 1.44269504f;
      al2[qq*4+2] = -__expf(a.z) * 1.44269504f;
      al2[qq*4+3] = -__expf(a.w) * 1.44269504f;
    }
  }
  const float dsk = Dskip[c];
  float h[16];
  {
    size_t off = ((size_t)(b * NCH + k) * 1536 + c) * 16;
    #pragma unroll
    for (int qq = 0; qq < 4; ++qq) ((float4*)h)[qq] = ((const float4*)&hstart[off])[qq];
  }
  __syncthreads();

  for (int t8 = 0; t8 < CT / 8; ++t8) {
    float dv[8], uv[8], gv[8];
    #pragma unroll
    for (int tt = 0; tt < 8; ++tt) {
      size_t row = rowbase + t8 * 8 + tt;
      dv[tt] = (float)dtb[row * 1536 + c];
      uv[tt] = (float)ub[row * 1536 + c];
      float zv = (float)xzb[row * 3072 + 1536 + c];
      gv[tt] = zv / (1.f + __expf(-zv));
    }
    #pragma unroll
    for (int tt = 0; tt < 8; ++tt) {
      float d = dv[tt], x = d * uv[tt];
      float BC[32];
      const float4* bp = (const float4*)&BCs[(t8 * 8 + tt) * 32];
      #pragma unroll
      for (int qq = 0; qq < 8; ++qq) ((float4*)BC)[qq] = bp[qq];
      float y = 0.f;
      #pragma unroll
      for (int n = 0; n < 16; ++n) {
        float e = exp2f(d * al2[n]);
        h[n] = h[n] * e + x * BC[n];
        y += h[n] * BC[16 + n];
      }
      size_t row = rowbase + t8 * 8 + tt;
      yg[row * 1536 + c] = (bf16)((y + uv[tt] * dsk) * gv[tt]);
    }
  }
}

extern "C" void kernel_launch(void* const* d_in, const int* in_sizes, int n_in,
                              void* d_out, int out_size, void* d_ws, size_t ws_size,
                              hipStream_t stream) {
  const float* x     = (const float*)d_in[0];
  const float* ln1w  = (const float*)d_in[1];
  const float* ln1b  = (const float*)d_in[2];
  const float* W_in  = (const float*)d_in[3];
  const float* convw = (const float*)d_in[4];
  const float* convb = (const float*)d_in[5];
  const float* W_x   = (const float*)d_in[6];
  const float* W_dt  = (const float*)d_in[7];
  const float* b_dt  = (const float*)d_in[8];
  const float* A_log = (const float*)d_in[9];
  const float* Dskip = (const float*)d_in[10];
  const float* W_out = (const float*)d_in[11];
  const float* ln2w  = (const float*)d_in[12];
  const float* ln2b  = (const float*)d_in[13];
  const float* W1    = (const float*)d_in[14];
  const float* b1    = (const float*)d_in[15];
  const float* W2    = (const float*)d_in[16];
  const float* b2    = (const float*)d_in[17];
  float* out = (float*)d_out;

  uint8_t* ws = (uint8_t*)d_ws;
  size_t off = 0;
  auto alloc = [&](size_t bytes) { void* p = ws + off; off = (off + bytes + 255) & ~(size_t)255; return p; };

  bf16*  wInb  = (bf16*)alloc(3072ull * 768 * 2);
  bf16*  wXb   = (bf16*)alloc(128ull * 1536 * 2);
  bf16*  wDtb  = (bf16*)alloc(1536ull * 64 * 2);
  bf16*  wOutb = (bf16*)alloc(768ull * 1536 * 2);
  bf16*  w1b   = (bf16*)alloc(3072ull * 768 * 2);
  bf16*  w2b   = (bf16*)alloc(768ull * 3072 * 2);
  bf16*  xln   = (bf16*)alloc(8192ull * 768 * 2);    // reused as m_ln; P overlay during scan
  bf16*  xz    = (bf16*)alloc(8192ull * 3072 * 2);   // reused as a1
  bf16*  u     = (bf16*)alloc(8192ull * 1536 * 2);
  float* xdblf = (float*)alloc(8192ull * 128 * 4);
  bf16*  xdblb = (bf16*)alloc(8192ull * 128 * 2);
  bf16*  dtb   = (bf16*)alloc(8192ull * 1536 * 2);
  bf16*  ygate = (bf16*)alloc(8192ull * 1536 * 2);
  float* hbuf  = (float*)alloc(8192ull * 768 * 4);   // hstart overlay during scan
  float* hendb = (float*)alloc(4ull * NCH * 1536 * 16 * 4);
  (void)ws_size; (void)in_sizes; (void)n_in; (void)out_size;

  float* Pbuf    = (float*)xln;
  float* hstartb = (float*)hbuf;

  cast_pad<<<dim3(3, 3072),  256, 0, stream>>>(W_in,  wInb,  768,  3072, 768);
  cast_pad<<<dim3(6, 128),   256, 0, stream>>>(W_x,   wXb,   1536, 80,   1536);
  cast_pad<<<dim3(1, 1536),  256, 0, stream>>>(W_dt,  wDtb,  64,   1536, 48);
  cast_pad<<<dim3(6, 768),   256, 0, stream>>>(W_out, wOutb, 1536, 768,  1536);
  cast_pad<<<dim3(3, 3072),  256, 0, stream>>>(W1,    w1b,   768,  3072, 768);
  cast_pad<<<dim3(12, 768),  256, 0, stream>>>(W2,    w2b,   3072, 768,  3072);

  ln_cast<<<8192, 256, 0, stream>>>(x, ln1w, ln1b, xln);

  // xz = ln(x) @ W_in^T
  gemm_bt<0><<<dim3(24, 64), 256, 0, stream>>>(xln, wInb, 3072, 768, 768, 768, xz, nullptr, nullptr, nullptr);
  conv_silu<<<dim3(6, 8192), 256, 0, stream>>>(xz, convw, convb, u);
  // x_dbl = u @ W_x^T (N padded to 128)
  gemm_bt<1><<<dim3(1, 64), 256, 0, stream>>>(u, wXb, 128, 1536, 1536, 1536, xdblf, xdblb, nullptr, nullptr);
  // dt = softplus(x_dbl[:, :48] @ W_dt^T + b_dt)
  gemm_bt<2><<<dim3(12, 64), 256, 0, stream>>>(xdblb, wDtb, 1536, 64, 128, 64, dtb, nullptr, b_dt, nullptr);
  // chunked scan
  scan_pass1<<<dim3(6, NCH, 4), 256, 0, stream>>>(dtb, u, xdblf, A_log, Pbuf, hendb);
  scan_pass2<<<384, 256, 0, stream>>>(Pbuf, hendb, hstartb);
  scan_pass3<<<dim3(6, NCH, 4), 256, 0, stream>>>(dtb, u, xz, xdblf, A_log, Dskip, hstartb, ygate);
  // h = x + y @ W_out^T
  gemm_bt<3><<<dim3(6, 64), 256, 0, stream>>>(ygate, wOutb, 768, 1536, 1536, 1536, hbuf, nullptr, nullptr, x);
  ln_cast<<<8192, 256, 0, stream>>>(hbuf, ln2w, ln2b, xln);
  // a1 = relu(m_ln @ W1^T + b1)
  gemm_bt<4><<<dim3(24, 64), 256, 0, stream>>>(xln, w1b, 3072, 768, 768, 768, xz, nullptr, b1, nullptr);
  // out = h + a1 @ W2^T + b2
  gemm_bt<5><<<dim3(6, 64), 256, 0, stream>>>(xz, w2b, 768, 3072, 3072, 3072, out, nullptr, b2, hbuf);
}